// Round 12
// baseline (792.936 us; speedup 1.0000x reference)
//
#include <hip/hip_runtime.h>
#include <math.h>

#define NB   2048
#define DIN  784
#define HN   256
#define NOUT 10
#define OSTR (HN + HN + NOUT)   // 522

// Per-block LDS: 8 batch rows (2 per wave). ~68 KB.
struct Smem {
  float4  sup[8][HN];      // 32 KB: (node, u, parent-logit, 0) per j
  double2 tab[65];         // 1040 B: {ln(k/64), 64/k}, k=64..128 (device-built)
  float   scr[8][16 * 20]; // 10 KB fold scratch
  float   h2o[8][HN];      // 8 KB
  float   h1n[8][HN];      // 8 KB
  float   tmp[8][HN];      // 8 KB
  float   yv [8][16];      // 512 B
};

// ---- bitwise replica of numpy's SIMD float32 exp ---------------------------
__device__ __forceinline__ float np_expf(float xf) {
  float q = __fmul_rn(xf, 1.442695040888963f);       // x * NPY_LOG2Ef
  q = __fadd_rn(q, 12582912.0f);                     // 0x1.8p23 round-to-even
  q = __fsub_rn(q, 12582912.0f);
  float x = __builtin_fmaf(q, -6.93145752e-1f, xf);  // Cody-Waite high
  x = __builtin_fmaf(q, -1.42860677e-6f, x);         // Cody-Waite low
  float num = __builtin_fmaf(x, 5.082762527590693718096e-04f,
                                6.757896990527504603057e-03f);
  num = __builtin_fmaf(num, x, 5.114512081637298353406e-02f);
  num = __builtin_fmaf(num, x, 2.473615434895520810817e-01f);
  num = __builtin_fmaf(num, x, 7.257664613233124478488e-01f);
  num = __builtin_fmaf(num, x, 9.999999999980870924916e-01f);
  float den = __builtin_fmaf(x, 2.159509375685829852307e-02f,
                                -2.742335390411667452936e-01f);
  den = __builtin_fmaf(den, x, 1.0f);
  float r = __fdiv_rn(num, den);
  int qi = (int)q;
  return __fmul_rn(r, __int_as_float((qi + 127) << 23));
}

// fp64 log1p for e in (0,1] — verbatim round 11 (zero flips measured).
__device__ __forceinline__ float np_log1pf(float ef, const double2* __restrict__ tab) {
  if (ef < 0x1p-29f) return ef;
  double t  = 1.0 + (double)ef;            // exact
  double kd = rint(t * 64.0);              // k in [64, 128]
  int   idx = (int)kd - 64;
  double2 te = tab[idx];                   // {ln(c), 64/k}
  double c  = kd * 0.015625;               // exact
  double s  = (t - c) * te.y;              // t-c exact (Sterbenz)
  double p  = fma(s, -1.0/6.0, 0.2);
  p = fma(p, s, -0.25);
  p = fma(p, s,  1.0/3.0);
  p = fma(p, s, -0.5);
  p = fma(p, s,  1.0);
  p = p * s;                               // ln(1+s)
  return (float)(te.x + p);
}

// sigmoid-CE, numpy op order
__device__ __forceinline__ float ce32(float l, float label, const double2* __restrict__ tab) {
  float t3 = __fsub_rn(fmaxf(l, 0.0f), __fmul_rn(l, label));
  return __fadd_rn(t3, np_log1pf(np_expf(-fabsf(l)), tab));
}

// divide-free decision (verbatim round 11)
__device__ __forceinline__ bool decide(float u, float ez) {
  float w = __fadd_rn(1.0f, ez);
  float d = __builtin_fmaf(u, w, -1.0f);
  if (__builtin_expect(fabsf(d) < 1e-5f, 0)) {
    float prob = __fdiv_rn(1.0f, w);
    return u < prob;
  }
  return d < 0.0f;
}

// lane data movement (bitwise-safe)
template<int CTRL> __device__ __forceinline__ float dppx(float v) {
  return __int_as_float(__builtin_amdgcn_mov_dpp(__float_as_int(v), CTRL, 0xF, 0xF, true));
}
__device__ __forceinline__ float rdl(float v, int l) {
  return __int_as_float(__builtin_amdgcn_readlane(__float_as_int(v), l));
}

// numpy pairwise sum over 10 on lanes 0..9
__device__ __forceinline__ float sum10(float c) {
  float c0 = rdl(c, 0), c1 = rdl(c, 1), c2 = rdl(c, 2), c3 = rdl(c, 3);
  float c4 = rdl(c, 4), c5 = rdl(c, 5), c6 = rdl(c, 6), c7 = rdl(c, 7);
  float c8 = rdl(c, 8), c9 = rdl(c, 9);
  float t = __fadd_rn(__fadd_rn(__fadd_rn(c0, c1), __fadd_rn(c2, c3)),
                      __fadd_rn(__fadd_rn(c4, c5), __fadd_rn(c6, c7)));
  t = __fadd_rn(t, c8);
  t = __fadd_rn(t, c9);
  return t;
}

// fold split into write / read halves so the two rows' folds interleave.
__device__ __forceinline__ void foldw(const float c[4], float* __restrict__ scrw,
                                      int idx, int g) {
  *reinterpret_cast<float4*>(scrw + idx * 20 + 4 * g) = make_float4(c[0], c[1], c[2], c[3]);
}
__device__ __forceinline__ float foldr(const float* __restrict__ scrw, int idx) {
  const float4* rp = reinterpret_cast<const float4*>(scrw + idx * 20);
  float4 q0 = rp[0], q1 = rp[1], q2 = rp[2], q3 = rp[3];
  float r = q0.x;
  r = __fadd_rn(r, q0.y); r = __fadd_rn(r, q0.z); r = __fadd_rn(r, q0.w);
  r = __fadd_rn(r, q1.x); r = __fadd_rn(r, q1.y); r = __fadd_rn(r, q1.z); r = __fadd_rn(r, q1.w);
  r = __fadd_rn(r, q2.x); r = __fadd_rn(r, q2.y); r = __fadd_rn(r, q2.z); r = __fadd_rn(r, q2.w);
  r = __fadd_rn(r, q3.x); r = __fadd_rn(r, q3.y); r = __fadd_rn(r, q3.z); r = __fadd_rn(r, q3.w);
  r = __fadd_rn(r, dppx<0xB1>(r));      // xor 1
  r = __fadd_rn(r, dppx<0x4E>(r));      // xor 2
  float B0 = rdl(r, 0), B1 = rdl(r, 4), B2 = rdl(r, 8), B3 = rdl(r, 12);
  return __fadd_rn(__fadd_rn(B0, B1), __fadd_rn(B2, B3));
}

__global__ __launch_bounds__(256) void stoch_mlp(
    const float* __restrict__ x,  const int* __restrict__ h1,
    const int* __restrict__ h2,   const int* __restrict__ y,
    const float* __restrict__ W1, const float* __restrict__ b1,
    const float* __restrict__ W2, const float* __restrict__ b2,
    const float* __restrict__ Wo, const float* __restrict__ bo,
    const float* __restrict__ u1, const float* __restrict__ u2,
    float* __restrict__ out)
{
  __shared__ Smem sm;
  const int t    = threadIdx.x;
  const int lane = t & 63;
  const int wid  = t >> 6;
  const int b0   = blockIdx.x * 8;        // 8 rows per block, 2 per wave
  const int rA   = 2 * wid, rB = rA + 1;  // row slots in block
  const int bA   = b0 + rA, bB = b0 + rB; // global batch rows

  // ---- phase 1: tables, states, pl1 = x@W1 (BLAS fp32, 8 rows) -----------
  if (t < 65) {
    double c = (double)(t + 64) * 0.015625;
    sm.tab[t] = make_double2(log(c), 64.0 / (double)(t + 64));
  }
  for (int j = lane; j < HN; j += 64) {
    sm.h2o[rA][j] = (float)h2[bA * HN + j];
    sm.h2o[rB][j] = (float)h2[bB * HN + j];
  }
  if (lane < 16) {
    sm.yv[rA][lane] = (lane < NOUT) ? (float)y[bA * NOUT + lane] : 0.0f;
    sm.yv[rB][lane] = (lane < NOUT) ? (float)y[bB * NOUT + lane] : 0.0f;
  }
  {
    float a[8] = {0,0,0,0,0,0,0,0};       // 8 sequential-k FMA chains
    const float* x0 = x + (size_t)b0 * DIN;
    for (int k = 0; k < DIN; ++k) {
      float wk = W1[k * HN + t];
      #pragma unroll
      for (int r = 0; r < 8; ++r)
        a[r] = __builtin_fmaf(x0[r * DIN + k], wk, a[r]);
    }
    float bb = b1[t];
    float4 uv0 = *reinterpret_cast<const float4*>(u1 + (size_t)t * NB + b0);
    float4 uv1 = *reinterpret_cast<const float4*>(u1 + (size_t)t * NB + b0 + 4);
    float uu[8] = {uv0.x, uv0.y, uv0.z, uv0.w, uv1.x, uv1.y, uv1.z, uv1.w};
    #pragma unroll
    for (int r = 0; r < 8; ++r) {
      float n = (float)h1[(b0 + r) * HN + t];
      sm.sup[r][t] = make_float4(n, uu[r], __fadd_rn(a[r], bb), 0.0f);
    }
  }
  __syncthreads();

  const double2* tab = sm.tab;
  float* scrA = &sm.scr[rA][0];
  float* scrB = &sm.scr[rB][0];

  // nl-init = h1_old @ W2 + b2 for both rows (masked fp32 == BLAS chain)
  {
    float aA[4] = {0,0,0,0}, aB[4] = {0,0,0,0};
    for (int j = 0; j < HN; ++j) {
      float4 wf = *reinterpret_cast<const float4*>(W2 + (size_t)j * HN + 4*lane);
      if (sm.sup[rA][j].x != 0.0f) {
        aA[0] = __fadd_rn(aA[0], wf.x); aA[1] = __fadd_rn(aA[1], wf.y);
        aA[2] = __fadd_rn(aA[2], wf.z); aA[3] = __fadd_rn(aA[3], wf.w);
      }
      if (sm.sup[rB][j].x != 0.0f) {
        aB[0] = __fadd_rn(aB[0], wf.x); aB[1] = __fadd_rn(aB[1], wf.y);
        aB[2] = __fadd_rn(aB[2], wf.z); aB[3] = __fadd_rn(aB[3], wf.w);
      }
    }
    float4 bv = *reinterpret_cast<const float4*>(b2 + 4*lane);
    *reinterpret_cast<float4*>(&sm.tmp[rA][4*lane]) =
        make_float4(__fadd_rn(aA[0], bv.x), __fadd_rn(aA[1], bv.y),
                    __fadd_rn(aA[2], bv.z), __fadd_rn(aA[3], bv.w));
    *reinterpret_cast<float4*>(&sm.tmp[rB][4*lane]) =
        make_float4(__fadd_rn(aB[0], bv.x), __fadd_rn(aB[1], bv.y),
                    __fadd_rn(aB[2], bv.z), __fadd_rn(aB[3], bv.w));
  }

  // ---- phase 2: layer-0 scan, two rows interleaved ------------------------
  const int idx  = lane & 15;
  const int g    = lane >> 4;
  const int half = idx >> 3;
  const int jacc = idx & 7;
  const int kb   = half * 128 + (4 * g) * 8 + jacc;

  float nlvA[4], nvA[4], nlvB[4], nvB[4], wv[4];
  #pragma unroll
  for (int i = 0; i < 4; ++i) {
    int k = kb + i * 8;
    nlvA[i] = sm.tmp[rA][k]; nvA[i] = sm.h2o[rA][k];
    nlvB[i] = sm.tmp[rB][k]; nvB[i] = sm.h2o[rB][k];
    wv[i]   = W2[k];                   // shared weight prefetch (row 0)
  }
  float S_cA, S_cB;
  {
    float cA[4], cB[4];
    #pragma unroll
    for (int i = 0; i < 4; ++i) cA[i] = ce32(nlvA[i], nvA[i], tab);
    foldw(cA, scrA, idx, g);
    #pragma unroll
    for (int i = 0; i < 4; ++i) cB[i] = ce32(nlvB[i], nvB[i], tab);
    foldw(cB, scrB, idx, g);
    S_cA = foldr(scrA, idx);
    S_cB = foldr(scrB, idx);
  }

  {
    float4 supCA = sm.sup[rA][0], supCB = sm.sup[rB][0];
    for (int j = 0; j < HN; ++j) {
      int jn = (j + 1) & (HN - 1);
      float4 supNA = sm.sup[rA][jn], supNB = sm.sup[rB][jn];
      float wcur[4];
      #pragma unroll
      for (int i = 0; i < 4; ++i) wcur[i] = wv[i];
      #pragma unroll
      for (int i = 0; i < 4; ++i) wv[i] = W2[(size_t)jn * HN + kb + i * 8];

      // --- row A fresh CE + fold write ---
      float nodeA = supCA.x, uA = supCA.y, plA = supCA.z;
      bool  ndA = (nodeA != 0.0f);
      float omA = __fsub_rn(1.0f, nodeA);
      float nl0A[4], nl1A[4], chgA[4];
      #pragma unroll
      for (int i = 0; i < 4; ++i) {
        nl0A[i] = __fsub_rn(nlvA[i], __fmul_rn(nodeA, wcur[i]));
        nl1A[i] = __fadd_rn(nlvA[i], __fmul_rn(omA,   wcur[i]));
        chgA[i] = ce32(ndA ? nl0A[i] : nl1A[i], nvA[i], tab);
      }
      foldw(chgA, scrA, idx, g);

      // --- row B fresh CE + fold write (covers A's LDS round-trip) ---
      float nodeB = supCB.x, uB = supCB.y, plB = supCB.z;
      bool  ndB = (nodeB != 0.0f);
      float omB = __fsub_rn(1.0f, nodeB);
      float nl0B[4], nl1B[4], chgB[4];
      #pragma unroll
      for (int i = 0; i < 4; ++i) {
        nl0B[i] = __fsub_rn(nlvB[i], __fmul_rn(nodeB, wcur[i]));
        nl1B[i] = __fadd_rn(nlvB[i], __fmul_rn(omB,   wcur[i]));
        chgB[i] = ce32(ndB ? nl0B[i] : nl1B[i], nvB[i], tab);
      }
      foldw(chgB, scrB, idx, g);

      // --- row A fold read + decide ---
      float FA  = foldr(scrA, idx);
      float S0A = ndA ? FA : S_cA;
      float S1A = ndA ? S_cA : FA;
      float zA  = __fsub_rn(__fadd_rn(plA, -S1A), -S0A);
      float ezA = np_expf(-zA);

      // --- row B fold read ---
      float FB  = foldr(scrB, idx);
      float S0B = ndB ? FB : S_cB;
      float S1B = ndB ? S_cB : FB;
      float zB  = __fsub_rn(__fadd_rn(plB, -S1B), -S0B);
      float ezB = np_expf(-zB);

      bool nwA = decide(uA, ezA);
      #pragma unroll
      for (int i = 0; i < 4; ++i) nlvA[i] = nwA ? nl1A[i] : nl0A[i];
      S_cA = (nwA != ndA) ? FA : S_cA;
      if (lane == 0) sm.h1n[rA][j] = nwA ? 1.0f : 0.0f;

      bool nwB = decide(uB, ezB);
      #pragma unroll
      for (int i = 0; i < 4; ++i) nlvB[i] = nwB ? nl1B[i] : nl0B[i];
      S_cB = (nwB != ndB) ? FB : S_cB;
      if (lane == 0) sm.h1n[rB][j] = nwB ? 1.0f : 0.0f;

      supCA = supNA; supCB = supNB;
    }
  }

  // ---- phase 3: pl2 = h1_new @ W2 + b2 (both rows); repack staging --------
  {
    float aA[4] = {0,0,0,0}, aB[4] = {0,0,0,0};
    for (int j = 0; j < HN; ++j) {
      float4 wf = *reinterpret_cast<const float4*>(W2 + (size_t)j * HN + 4*lane);
      if (sm.h1n[rA][j] != 0.0f) {
        aA[0] = __fadd_rn(aA[0], wf.x); aA[1] = __fadd_rn(aA[1], wf.y);
        aA[2] = __fadd_rn(aA[2], wf.z); aA[3] = __fadd_rn(aA[3], wf.w);
      }
      if (sm.h1n[rB][j] != 0.0f) {
        aB[0] = __fadd_rn(aB[0], wf.x); aB[1] = __fadd_rn(aB[1], wf.y);
        aB[2] = __fadd_rn(aB[2], wf.z); aB[3] = __fadd_rn(aB[3], wf.w);
      }
    }
    float4 bv = *reinterpret_cast<const float4*>(b2 + 4*lane);
    float p2A[4] = {__fadd_rn(aA[0], bv.x), __fadd_rn(aA[1], bv.y),
                    __fadd_rn(aA[2], bv.z), __fadd_rn(aA[3], bv.w)};
    float p2B[4] = {__fadd_rn(aB[0], bv.x), __fadd_rn(aB[1], bv.y),
                    __fadd_rn(aB[2], bv.z), __fadd_rn(aB[3], bv.w)};
    #pragma unroll
    for (int i = 0; i < 4; ++i) {
      int jj = 4 * lane + i;
      sm.sup[rA][jj] = make_float4(sm.h2o[rA][jj], u2[(size_t)jj * NB + bA], p2A[i], 0.0f);
      sm.sup[rB][jj] = make_float4(sm.h2o[rB][jj], u2[(size_t)jj * NB + bB], p2B[i], 0.0f);
    }
  }

  // layer-1 init: nlo = h2_old @ Wout + bout (both rows)
  float nvyA = 0.0f, nloA = 0.0f, nvyB = 0.0f, nloB = 0.0f;
  if (lane < NOUT) {
    nvyA = sm.yv[rA][lane];  nvyB = sm.yv[rB][lane];
    float aA = 0.0f, aB = 0.0f;
    for (int j = 0; j < HN; ++j) {
      float wj = Wo[j * NOUT + lane];
      if (sm.h2o[rA][j] != 0.0f) aA = __fadd_rn(aA, wj);
      if (sm.h2o[rB][j] != 0.0f) aB = __fadd_rn(aB, wj);
    }
    nloA = __fadd_rn(aA, bo[lane]);
    nloB = __fadd_rn(aB, bo[lane]);
  }
  float S_c1A = sum10((lane < NOUT) ? ce32(nloA, nvyA, tab) : 0.0f);
  float S_c1B = sum10((lane < NOUT) ? ce32(nloB, nvyB, tab) : 0.0f);

  // ---- phase 4: layer-1 scan, two rows interleaved ------------------------
  {
    float w = (lane < NOUT) ? Wo[lane] : 0.0f;
    float4 sCA = sm.sup[rA][0], sCB = sm.sup[rB][0];
    for (int j = 0; j < HN; ++j) {
      int jn = (j + 1) & (HN - 1);
      float4 sNA = sm.sup[rA][jn], sNB = sm.sup[rB][jn];
      float wn = (lane < NOUT) ? Wo[jn * NOUT + lane] : 0.0f;

      float nodeA = sCA.x, uA = sCA.y, plA = sCA.z;
      bool  ndA = (nodeA != 0.0f);
      float omA = __fsub_rn(1.0f, nodeA);
      float nl0A = __fsub_rn(nloA, __fmul_rn(nodeA, w));
      float nl1A = __fadd_rn(nloA, __fmul_rn(omA,   w));
      float chgA = (lane < NOUT) ? ce32(ndA ? nl0A : nl1A, nvyA, tab) : 0.0f;

      float nodeB = sCB.x, uB = sCB.y, plB = sCB.z;
      bool  ndB = (nodeB != 0.0f);
      float omB = __fsub_rn(1.0f, nodeB);
      float nl0B = __fsub_rn(nloB, __fmul_rn(nodeB, w));
      float nl1B = __fadd_rn(nloB, __fmul_rn(omB,   w));
      float chgB = (lane < NOUT) ? ce32(ndB ? nl0B : nl1B, nvyB, tab) : 0.0f;

      float FA  = sum10(chgA);
      float S0A = ndA ? FA : S_c1A;
      float S1A = ndA ? S_c1A : FA;
      float zA  = __fsub_rn(__fadd_rn(plA, -S1A), -S0A);
      float ezA = np_expf(-zA);

      float FB  = sum10(chgB);
      float S0B = ndB ? FB : S_c1B;
      float S1B = ndB ? S_c1B : FB;
      float zB  = __fsub_rn(__fadd_rn(plB, -S1B), -S0B);
      float ezB = np_expf(-zB);

      bool nwA = decide(uA, ezA);
      nloA  = nwA ? nl1A : nl0A;
      S_c1A = (nwA != ndA) ? FA : S_c1A;
      if (lane == 0) out[(size_t)bA * OSTR + HN + j] = nwA ? 1.0f : 0.0f;

      bool nwB = decide(uB, ezB);
      nloB  = nwB ? nl1B : nl0B;
      S_c1B = (nwB != ndB) ? FB : S_c1B;
      if (lane == 0) out[(size_t)bB * OSTR + HN + j] = nwB ? 1.0f : 0.0f;

      sCA = sNA; sCB = sNB; w = wn;
    }
  }

  // ---- phase 5: outputs (both rows) ---------------------------------------
  float* orA = out + (size_t)bA * OSTR;
  float* orB = out + (size_t)bB * OSTR;
  for (int j = lane; j < HN; j += 64) {
    orA[j] = sm.h1n[rA][j];
    orB[j] = sm.h1n[rB][j];
  }
  if (lane < NOUT) {
    orA[2*HN + lane] = nloA;
    orB[2*HN + lane] = nloB;
  }
}

extern "C" void kernel_launch(void* const* d_in, const int* in_sizes, int n_in,
                              void* d_out, int out_size, void* d_ws, size_t ws_size,
                              hipStream_t stream) {
  const float* x  = (const float*)d_in[0];
  const int*   h1 = (const int*)  d_in[1];
  const int*   h2 = (const int*)  d_in[2];
  const int*   y  = (const int*)  d_in[3];
  const float* W1 = (const float*)d_in[4];
  const float* b1 = (const float*)d_in[5];
  const float* W2 = (const float*)d_in[6];
  const float* b2 = (const float*)d_in[7];
  const float* Wo = (const float*)d_in[8];
  const float* bo = (const float*)d_in[9];
  const float* u1 = (const float*)d_in[10];
  const float* u2 = (const float*)d_in[11];
  stoch_mlp<<<NB/8, 256, 0, stream>>>(x, h1, h2, y, W1, b1, W2, b2, Wo, bo, u1, u2,
                                      (float*)d_out);
}